// Round 6
// baseline (159.404 us; speedup 1.0000x reference)
//
#include <hip/hip_runtime.h>

typedef _Float16 half8 __attribute__((ext_vector_type(8)));
typedef float    f32x16 __attribute__((ext_vector_type(16)));

constexpr int kH = 16;    // heads
constexpr int kO = 1024;  // codebook options
constexpr int kA = 128;   // head size
constexpr int kBS = 4096; // B*S positions
constexpr int MTILE = 64; // positions per block
constexpr int NITER = 16; // option-tiles (32 options) per wave

// ---- Pass 1: split W into fp16 hi/lo planes, packed fragment-major ----
// Packed (halfs): tile_base = (h*32 + t)*8192, plane*4096, + (a>>4)*512
//                 + (((a>>3)&1)*32 + (o&31))*8 + (a&7)
// Wave-per-row: lane L reads float2 at a=2L (coalesced 512 B), scatter-writes ushort2.
__global__ void split_w(const float* __restrict__ w, ushort* __restrict__ wp) {
    const int lane = threadIdx.x & 63;
    const int gw   = blockIdx.x * 4 + (threadIdx.x >> 6);
    const int ks   = lane >> 3;          // (2L)>>4
    const int half = (lane >> 2) & 1;    // ((2L)>>3)&1
    const int j    = (2 * lane) & 7;
#pragma unroll
    for (int q = 0; q < 4; ++q) {
        int r = gw * 4 + q;              // global row: h*1024 + o
        int h = r >> 10, o = r & 1023, t = o >> 5, o31 = o & 31;
        float2 v = *(const float2*)(w + r * kA + lane * 2);
        _Float16 h0 = (_Float16)v.x, h1 = (_Float16)v.y;
        _Float16 l0 = (_Float16)(v.x - (float)h0), l1 = (_Float16)(v.y - (float)h1);
        ushort2 hv = { __builtin_bit_cast(ushort, h0), __builtin_bit_cast(ushort, h1) };
        ushort2 lv = { __builtin_bit_cast(ushort, l0), __builtin_bit_cast(ushort, l1) };
        ushort* d = wp + (h * 32 + t) * 8192 + ks * 512 + (half * 32 + o31) * 8 + j;
        *(ushort2*)d = hv;               // plane 0 (hi)
        *(ushort2*)(d + 4096) = lv;      // plane 1 (lo)
    }
}

// ---- Pass 2: fused logits (fp16-split, fp32 accum) + argmax + gather ----
// Full-tile register double-buffer: issue ALL 16 loads of tile it+1 BEFORE
// computing tile it (24 MFMAs + fold cover the latency structurally).
__launch_bounds__(256, 2)
__global__ void vq_argmax_gather(const float* __restrict__ x,
                                 const ushort* __restrict__ wp,
                                 const float* __restrict__ cb,
                                 float* __restrict__ out) {
    __shared__ float red_max[2][MTILE];
    __shared__ int   red_idx[2][MTILE];

    const int tid   = threadIdx.x;
    const int lane  = tid & 63;
    const int wv    = tid >> 6;
    const int nhalf = wv >> 1;
    const int mtile = wv & 1;
    const int bid   = blockIdx.x;
    // XCD-aware: XCD (bid&7) touches only heads {2x,2x+1} -> W+cb L2-resident
    const int h  = ((bid & 7) << 1) | ((bid >> 3) & 1);
    const int p0 = (bid >> 4) * MTILE;

    const int l31  = lane & 31;
    const int half = lane >> 5;

    // per-wave packed-W base: tiles t = nhalf*16 + it, 8192 halfs/tile (hi+lo)
    const ushort* wbase = wp + (h * 32 + nhalf * 16) * 8192 + lane * 8;

    uint4 bufA[16], bufB[16];            // [0..7]=hi plane, [8..15]=lo plane
    auto loadTile = [&](uint4* buf, int it) {
        const ushort* p = wbase + it * 8192;
#pragma unroll
        for (int ks = 0; ks < 8; ++ks) {
            buf[ks]     = *(const uint4*)(p + ks * 512);          // hi
            buf[8 + ks] = *(const uint4*)(p + 4096 + ks * 512);   // lo
        }
    };

    loadTile(bufA, 0);   // tile-0 latency hidden under x load/convert

    // stationary x fragments (fp32 -> fp16 hi/lo in-register)
    const int mrow = p0 + mtile * 32 + l31;
    const float* xbase = x + (mrow * kH + h) * kA + half * 8;
    half8 xh[8], xl[8];
#pragma unroll
    for (int ks = 0; ks < 8; ++ks) {
        float4 v0 = *(const float4*)(xbase + ks * 16);
        float4 v1 = *(const float4*)(xbase + ks * 16 + 4);
        float va[8] = { v0.x, v0.y, v0.z, v0.w, v1.x, v1.y, v1.z, v1.w };
        half8 hi, lo;
#pragma unroll
        for (int j = 0; j < 8; ++j) {
            _Float16 hj = (_Float16)va[j];
            hi[j] = hj;
            lo[j] = (_Float16)(va[j] - (float)hj);
        }
        xh[ks] = hi; xl[ks] = lo;
    }

    float best = -1e30f;
    int   bidx = 0;
    const int nwb = nhalf * (kO / 2);

    auto computeTile = [&](const uint4* buf, int it) {
        f32x16 acc = {};
#pragma unroll
        for (int ks = 0; ks < 8; ++ks)
            acc = __builtin_amdgcn_mfma_f32_32x32x16_f16(
                __builtin_bit_cast(half8, buf[ks]), xh[ks], acc, 0, 0, 0);
#pragma unroll
        for (int ks = 0; ks < 8; ++ks)
            acc = __builtin_amdgcn_mfma_f32_32x32x16_f16(
                __builtin_bit_cast(half8, buf[ks]), xl[ks], acc, 0, 0, 0);
#pragma unroll
        for (int ks = 0; ks < 8; ++ks)
            acc = __builtin_amdgcn_mfma_f32_32x32x16_f16(
                __builtin_bit_cast(half8, buf[8 + ks]), xh[ks], acc, 0, 0, 0);
        // fold 16 option-rows into running scalar argmax (rows ascend with r)
        float lv = acc[0];
        int   lr = 0;
#pragma unroll
        for (int r = 1; r < 16; ++r) {
            if (acc[r] > lv) { lv = acc[r]; lr = r; }   // strict >: earliest row wins
        }
        int li = nwb + it * 32 + 4 * half + (lr & 3) + 8 * (lr >> 2);
        if (lv > best) { best = lv; bidx = li; }        // strict >: earlier tile wins
    };

    // ping-pong: loads of tile k+1 issue BEFORE tile k's MFMAs consume their buffer
    for (int it2 = 0; it2 < NITER; it2 += 2) {
        loadTile(bufB, it2 + 1);
        computeTile(bufA, it2);
        if (it2 + 2 < NITER) loadTile(bufA, it2 + 2);
        computeTile(bufB, it2 + 1);
    }

    // merge lane halves (disjoint option rows, same position column)
    {
        float om = __shfl_xor(best, 32, 64);
        int   oi = __shfl_xor(bidx, 32, 64);
        if (om > best || (om == best && oi < bidx)) { best = om; bidx = oi; }
    }
    if (half == 0) {
        red_max[nhalf][mtile * 32 + l31] = best;
        red_idx[nhalf][mtile * 32 + l31] = bidx;
    }
    __syncthreads();

    // gather: out[p0+row, h, :] = cb[h, argmax, :]
    for (int i = tid; i < MTILE * 32; i += 256) {
        int row = i >> 5, ch = i & 31;
        float m0 = red_max[0][row], m1 = red_max[1][row];
        int o = (m1 > m0) ? red_idx[1][row] : red_idx[0][row]; // ties -> smaller o
        float4 v = *(const float4*)(cb + (h * kO + o) * kA + ch * 4);
        *(float4*)(out + ((p0 + row) * kH + h) * kA + ch * 4) = v;
    }
}

extern "C" void kernel_launch(void* const* d_in, const int* in_sizes, int n_in,
                              void* d_out, int out_size, void* d_ws, size_t ws_size,
                              hipStream_t stream) {
    const float* x  = (const float*)d_in[0];   // [4096,16,128] fp32
    const float* w  = (const float*)d_in[1];   // [16,1024,128] fp32
    const float* cb = (const float*)d_in[2];   // [16,1024,128] fp32
    // d_in[3] = temperature: forward value is temperature-independent
    float* out = (float*)d_out;                // [4096,16,128] fp32

    ushort* wpacked = (ushort*)d_ws;           // 8 MiB packed hi+lo planes

    split_w<<<dim3(1024), dim3(256), 0, stream>>>(w, wpacked);
    vq_argmax_gather<<<dim3((kBS / MTILE) * kH), dim3(256), 0, stream>>>(x, wpacked, cb, out);
}

// Round 7
// 152.952 us; speedup vs baseline: 1.0422x; 1.0422x over previous
//
#include <hip/hip_runtime.h>

typedef _Float16 half8 __attribute__((ext_vector_type(8)));
typedef float    f32x16 __attribute__((ext_vector_type(16)));

constexpr int kH = 16;    // heads
constexpr int kO = 1024;  // codebook options
constexpr int kA = 128;   // head size
constexpr int kBS = 4096; // B*S positions
constexpr int MTILE = 64; // positions per block
constexpr int NITER = 16; // option-tiles (32 options) per wave

typedef const __attribute__((address_space(1))) uint32_t* gas_ptr;
typedef __attribute__((address_space(3))) uint32_t* las_ptr;

// ---- Pass 1: split W into fp16 hi/lo planes, packed fragment-major ----
// Packed (halfs): (h*32 + t)*8192 + plane*4096 + ks*512 + lane*8 + j
//   where t = o>>5, lane = half*32 + (o&31), ks = a>>4, half = (a>>3)&1, j = a&7
// Each (tile, plane, ks) chunk is 64 lanes x 16 B contiguous.
__global__ void split_w(const float* __restrict__ w, ushort* __restrict__ wp) {
    const int lane = threadIdx.x & 63;
    const int gw   = blockIdx.x * 4 + (threadIdx.x >> 6);
    const int ks   = lane >> 3;          // (2L)>>4
    const int half = (lane >> 2) & 1;    // ((2L)>>3)&1
    const int j    = (2 * lane) & 7;
#pragma unroll
    for (int q = 0; q < 4; ++q) {
        int r = gw * 4 + q;              // global row: h*1024 + o
        int h = r >> 10, o = r & 1023, t = o >> 5, o31 = o & 31;
        float2 v = *(const float2*)(w + r * kA + lane * 2);
        _Float16 h0 = (_Float16)v.x, h1 = (_Float16)v.y;
        _Float16 l0 = (_Float16)(v.x - (float)h0), l1 = (_Float16)(v.y - (float)h1);
        ushort2 hv = { __builtin_bit_cast(ushort, h0), __builtin_bit_cast(ushort, h1) };
        ushort2 lv = { __builtin_bit_cast(ushort, l0), __builtin_bit_cast(ushort, l1) };
        ushort* d = wp + (h * 32 + t) * 8192 + ks * 512 + (half * 32 + o31) * 8 + j;
        *(ushort2*)d = hv;               // plane 0 (hi)
        *(ushort2*)(d + 4096) = lv;      // plane 1 (lo)
    }
}

// ---- Pass 2: LDS double-buffered logits (fp16-split, fp32 accum) + argmax + gather ----
// Per iter: stage next 32-option tile (both nhalves, hi+lo = 32 KB) into LDS via
// global_load_lds (async DMA, no VGPR dest -> compiler can't sink it), compute
// current tile from LDS, one __syncthreads per iter (vmcnt drain is implicit).
__launch_bounds__(256, 2)
__global__ void vq_argmax_gather(const float* __restrict__ x,
                                 const ushort* __restrict__ wp,
                                 const float* __restrict__ cb,
                                 float* __restrict__ out) {
    __shared__ ushort wtile[2][2][8192];  // [buf][nhalf][plane*4096 + ks*512 + lane*8]
    __shared__ float red_max[2][MTILE];
    __shared__ int   red_idx[2][MTILE];

    const int tid   = threadIdx.x;
    const int lane  = tid & 63;
    const int wv    = tid >> 6;
    const int nhalf = wv >> 1;
    const int mtile = wv & 1;
    const int bid   = blockIdx.x;
    // XCD-aware: XCD (bid&7) touches only heads {2x,2x+1} -> W+cb L2-resident
    const int h  = ((bid & 7) << 1) | ((bid >> 3) & 1);
    const int p0 = (bid >> 4) * MTILE;

    const int l31  = lane & 31;
    const int half = lane >> 5;

    const ushort* wh_base = wp + h * 32 * 8192;   // this head's packed W

    // DMA: 32 chunks/iter (2 nhalf x 2 plane x 8 ks), 8 per wave; chunk
    // c = wv*8+q: nh = c>>4, rem = c&15 (plane*8+ks). Uniform LDS base,
    // HW scatters lane i at base + i*16 (== our packed order).
    auto stage = [&](int it, int buf) {
#pragma unroll
        for (int q = 0; q < 8; ++q) {
            int c   = wv * 8 + q;
            int nh  = c >> 4, rem = c & 15;
            const ushort* g = wh_base + (nh * 16 + it) * 8192 + rem * 512 + lane * 8;
            ushort* l = &wtile[buf][nh][rem * 512];
            __builtin_amdgcn_global_load_lds((gas_ptr)(const void*)g,
                                             (las_ptr)(void*)l, 16, 0, 0);
        }
    };

    stage(0, 0);   // tile-0 DMA in flight under the x load/convert phase

    // stationary x fragments (fp32 -> fp16 hi/lo in-register)
    const int mrow = p0 + mtile * 32 + l31;
    const float* xbase = x + (mrow * kH + h) * kA + half * 8;
    half8 xh[8], xl[8];
#pragma unroll
    for (int ks = 0; ks < 8; ++ks) {
        float4 v0 = *(const float4*)(xbase + ks * 16);
        float4 v1 = *(const float4*)(xbase + ks * 16 + 4);
        float va[8] = { v0.x, v0.y, v0.z, v0.w, v1.x, v1.y, v1.z, v1.w };
        half8 hi, lo;
#pragma unroll
        for (int j = 0; j < 8; ++j) {
            _Float16 hj = (_Float16)va[j];
            hi[j] = hj;
            lo[j] = (_Float16)(va[j] - (float)hj);
        }
        xh[ks] = hi; xl[ks] = lo;
    }

    float best = -1e30f;
    int   bidx = 0;
    const int nwb = nhalf * (kO / 2);

    __syncthreads();   // tile 0 staged (compiler drains vmcnt before s_barrier)

    for (int it = 0; it < NITER; ++it) {
        const int cur = it & 1;
        if (it + 1 < NITER) stage(it + 1, cur ^ 1);   // async into other buffer

        const ushort* lbase = &wtile[cur][nhalf][lane * 8];
        half8 wh[8], wl[8];
#pragma unroll
        for (int ks = 0; ks < 8; ++ks) {
            wh[ks] = *(const half8*)(lbase + ks * 512);          // ds_read_b128
            wl[ks] = *(const half8*)(lbase + 4096 + ks * 512);
        }
        f32x16 acc = {};
#pragma unroll
        for (int ks = 0; ks < 8; ++ks)
            acc = __builtin_amdgcn_mfma_f32_32x32x16_f16(wh[ks], xh[ks], acc, 0, 0, 0);
#pragma unroll
        for (int ks = 0; ks < 8; ++ks)
            acc = __builtin_amdgcn_mfma_f32_32x32x16_f16(wh[ks], xl[ks], acc, 0, 0, 0);
#pragma unroll
        for (int ks = 0; ks < 8; ++ks)
            acc = __builtin_amdgcn_mfma_f32_32x32x16_f16(wl[ks], xh[ks], acc, 0, 0, 0);

        // fold 16 option-rows into running scalar argmax (rows ascend with r)
        float lv = acc[0];
        int   lr = 0;
#pragma unroll
        for (int r = 1; r < 16; ++r) {
            if (acc[r] > lv) { lv = acc[r]; lr = r; }   // strict >: earliest row wins
        }
        int li = nwb + it * 32 + 4 * half + (lr & 3) + 8 * (lr >> 2);
        if (lv > best) { best = lv; bidx = li; }        // strict >: earlier tile wins

        __syncthreads();   // readers done with buf[cur] + next DMAs landed
    }

    // merge lane halves (disjoint option rows, same position column)
    {
        float om = __shfl_xor(best, 32, 64);
        int   oi = __shfl_xor(bidx, 32, 64);
        if (om > best || (om == best && oi < bidx)) { best = om; bidx = oi; }
    }
    if (half == 0) {
        red_max[nhalf][mtile * 32 + l31] = best;
        red_idx[nhalf][mtile * 32 + l31] = bidx;
    }
    __syncthreads();

    // gather: out[p0+row, h, :] = cb[h, argmax, :]
    for (int i = tid; i < MTILE * 32; i += 256) {
        int row = i >> 5, ch = i & 31;
        float m0 = red_max[0][row], m1 = red_max[1][row];
        int o = (m1 > m0) ? red_idx[1][row] : red_idx[0][row]; // ties -> smaller o
        float4 v = *(const float4*)(cb + (h * kO + o) * kA + ch * 4);
        *(float4*)(out + ((p0 + row) * kH + h) * kA + ch * 4) = v;
    }
}

extern "C" void kernel_launch(void* const* d_in, const int* in_sizes, int n_in,
                              void* d_out, int out_size, void* d_ws, size_t ws_size,
                              hipStream_t stream) {
    const float* x  = (const float*)d_in[0];   // [4096,16,128] fp32
    const float* w  = (const float*)d_in[1];   // [16,1024,128] fp32
    const float* cb = (const float*)d_in[2];   // [16,1024,128] fp32
    // d_in[3] = temperature: forward value is temperature-independent
    float* out = (float*)d_out;                // [4096,16,128] fp32

    ushort* wpacked = (ushort*)d_ws;           // 8 MiB packed hi+lo planes

    split_w<<<dim3(1024), dim3(256), 0, stream>>>(w, wpacked);
    vq_argmax_gather<<<dim3((kBS / MTILE) * kH), dim3(256), 0, stream>>>(x, wpacked, cb, out);
}